// Round 17
// baseline (304.022 us; speedup 1.0000x reference)
//
#include <hip/hip_runtime.h>
#include <hip/hip_bf16.h>
#include <cstddef>
#include <cstdint>

#define BATCH 8
#define SEQ   2048
#define DEMB  1024
#define DQ    512

typedef __attribute__((ext_vector_type(8))) _Float16 f16x8;
typedef __attribute__((ext_vector_type(4))) float f32x4;

#define MFMA16(a, b, c) __builtin_amdgcn_mfma_f32_16x16x32_f16((a), (b), (c), 0, 0, 0)

#define GLDS16(gp, lp) __builtin_amdgcn_global_load_lds(                      \
    (const __attribute__((address_space(1))) void*)(gp),                      \
    (__attribute__((address_space(3))) void*)(lp), 16, 0, 0)

#define VM_BAR(N)                                                             \
  asm volatile("s_waitcnt vmcnt(" #N ")\n\ts_barrier" ::: "memory")
#define VM_LGKM_BAR(N)                                                        \
  asm volatile("s_waitcnt vmcnt(" #N ") lgkmcnt(0)\n\ts_barrier" ::: "memory")

// ---------------------------------------------------------------------------
// Merged prep: blocks [0,8192) xprep; [8192,9728) wprep; [9728,9736) mprep.
// ---------------------------------------------------------------------------
__global__ __launch_bounds__(256) void prep_all(
    const float* __restrict__ x, _Float16* __restrict__ xh,
    const float* __restrict__ Wq, const float* __restrict__ Wk,
    const float* __restrict__ Wv, _Float16* __restrict__ wt,
    const int* __restrict__ maskg, int* __restrict__ pidx,
    int* __restrict__ cnt)
{
  const int bid = blockIdx.x;
  const int tid = threadIdx.x;

  if (bid < 8192) {
    size_t i = ((size_t)bid * 256 + tid) * 8;
    float4 a = *(const float4*)&x[i];
    float4 b = *(const float4*)&x[i + 4];
    f16x8 h;
    h[0] = (_Float16)a.x; h[1] = (_Float16)a.y;
    h[2] = (_Float16)a.z; h[3] = (_Float16)a.w;
    h[4] = (_Float16)b.x; h[5] = (_Float16)b.y;
    h[6] = (_Float16)b.z; h[7] = (_Float16)b.w;
    *(f16x8*)&xh[i] = h;
  } else if (bid < 9728) {
    int qidx = (bid - 8192) * 256 + tid;
    int w   = qidx >> 17;
    int rem = qidx & 131071;
    int k   = rem >> 7;
    int n   = (rem & 127) * 4;
    const float* W = (w == 0) ? Wq : (w == 1) ? Wk : Wv;
    float4 v = *(const float4*)&W[(size_t)k * DQ + n];
    _Float16* dst = wt + (size_t)w * (DQ * DEMB);
    dst[(size_t)(n + 0) * DEMB + k] = (_Float16)v.x;
    dst[(size_t)(n + 1) * DEMB + k] = (_Float16)v.y;
    dst[(size_t)(n + 2) * DEMB + k] = (_Float16)v.z;
    dst[(size_t)(n + 3) * DEMB + k] = (_Float16)v.w;
  } else {
    const int b = bid - 9728;
    __shared__ int tsum[256];
    int mv[8], s = 0;
    #pragma unroll
    for (int j = 0; j < 8; j++) {
      mv[j] = maskg[b * SEQ + tid * 8 + j];
      s += mv[j];
    }
    tsum[tid] = s;
    __syncthreads();
    for (int d = 1; d < 256; d <<= 1) {
      int v = (tid >= d) ? tsum[tid - d] : 0;
      __syncthreads();
      tsum[tid] += v;
      __syncthreads();
    }
    if (tid == 255) cnt[b] = tsum[255];
    int run = tsum[tid] - s;
    #pragma unroll
    for (int j = 0; j < 8; j++) {
      pidx[b * SEQ + tid * 8 + j] = mv[j] ? run : -1;
      run += mv[j];
    }
  }
}

// ---------------------------------------------------------------------------
// Projection GEMM 3-in-1 (r16; setprio removed per m190 lockstep evidence).
// ---------------------------------------------------------------------------
__global__ __launch_bounds__(512, 2) void proj3(
    const _Float16* __restrict__ xh, const _Float16* __restrict__ wt,
    const int* __restrict__ pidx,
    _Float16* __restrict__ kf, _Float16* __restrict__ vt,
    _Float16* __restrict__ qpack)
{
  const int mt = blockIdx.y, nt = blockIdx.x;

  __shared__ _Float16 Xs[128][40];       // 10KB
  __shared__ _Float16 Ws[3][256][40];    // 60KB

  const int tid  = threadIdx.x;
  const int wave = tid >> 6, l = tid & 63;
  const int wm = wave >> 2;              // 0..1  (64-row group)
  const int wn = wave & 3;               // 0..3  (64-col group)
  const int lo4 = l & 15, hi2 = l >> 4;

  f32x4 acc[3][4][4];
  #pragma unroll
  for (int w = 0; w < 3; w++)
    #pragma unroll
    for (int mf = 0; mf < 4; mf++)
      #pragma unroll
      for (int nf = 0; nf < 4; nf++)
        #pragma unroll
        for (int i = 0; i < 4; i++) acc[w][mf][nf][i] = 0.f;

  const int    xsrow = tid >> 2;
  const int    xskh  = (tid & 3) * 8;
  const size_t xbase = (size_t)(mt * 128 + xsrow) * DEMB + xskh;
  const int    wsrow = tid >> 1;
  const int    wskh  = (tid & 1) * 16;
  const size_t wbase = (size_t)(nt * 256 + wsrow) * DEMB + wskh;

  #pragma unroll 1
  for (int k0 = 0; k0 < DEMB; k0 += 32) {
    *(f16x8*)&Xs[xsrow][xskh] = *(const f16x8*)&xh[xbase + k0];
    #pragma unroll
    for (int w = 0; w < 3; w++) {
      const size_t wb = (size_t)w * (DQ * DEMB) + wbase + k0;
      *(f16x8*)&Ws[w][wsrow][wskh]     = *(const f16x8*)&wt[wb];
      *(f16x8*)&Ws[w][wsrow][wskh + 8] = *(const f16x8*)&wt[wb + 8];
    }
    __syncthreads();

    f16x8 a[4];
    #pragma unroll
    for (int mf = 0; mf < 4; mf++)
      a[mf] = *(const f16x8*)&Xs[wm*64 + mf*16 + lo4][hi2*8];
    #pragma unroll
    for (int w = 0; w < 3; w++) {
      f16x8 bfr[4];
      #pragma unroll
      for (int nf = 0; nf < 4; nf++)
        bfr[nf] = *(const f16x8*)&Ws[w][wn*64 + nf*16 + lo4][hi2*8];
      #pragma unroll
      for (int mf = 0; mf < 4; mf++)
        #pragma unroll
        for (int nf = 0; nf < 4; nf++)
          acc[w][mf][nf] = MFMA16(a[mf], bfr[nf], acc[w][mf][nf]);
    }
    __syncthreads();
  }

  const int mb = mt * 128 + wm * 64;
  const int nb = nt * 256 + wn * 64;
  #pragma unroll
  for (int mf = 0; mf < 4; mf++)
    #pragma unroll
    for (int nf = 0; nf < 4; nf++)
      #pragma unroll
      for (int i = 0; i < 4; i++) {
        int m = mb + mf*16 + hi2*4 + i;
        int n = nb + nf*16 + lo4;
        {
          float val = acc[0][mf][nf][i];
          _Float16 h  = (_Float16)val;
          _Float16 lo = (_Float16)(val - (float)h);
          size_t base = (size_t)(m >> 6) * 65536 + (size_t)(m & 63) * 512 + n;
          qpack[base]         = h;
          qpack[base + 32768] = lo;
        }
        int d_ = pidx[m];
        if (d_ >= 0) {
          kf[((size_t)((m >> 11) << 11) + d_) * 512 + n]
              = (_Float16)acc[1][mf][nf][i];
          vt[(size_t)(m >> 11) * (512 * 2048) + (size_t)n * 2048 + d_]
              = (_Float16)acc[2][mf][nf][i];
        }
      }
}

// ---------------------------------------------------------------------------
// Flash attention v10 = r15's 150µs v9 pipeline with three micro-cuts:
//  (1) setprio removed (m190: hurts lockstep structures);
//  (2) 4 QK accumulator chains (Sh/Sl split, summed pre-softmax — r8-validated
//      summation regrouping, same absmax);
//  (3) defer-max guard: skip the o/o_ones rescale when no row max grew
//      (oscale==1 exactly -> bit-identical output).
// ---------------------------------------------------------------------------
__global__ __launch_bounds__(512, 2) void flash_v10(
    const _Float16* __restrict__ kfp, const _Float16* __restrict__ vtp,
    const int* __restrict__ cntg,
    float* dout)                          // aliases Q storage - no restrict
{
  const int bb = blockIdx.x & 7;          // batch -> XCD pin
  const int qt = blockIdx.x >> 3;         // 0..31
  const int q0 = qt * 64;

  const int tid = threadIdx.x;
  const int w = tid >> 6, l = tid & 63;
  const int qw = w & 3;                   // 16-row group
  const int kw = w >> 2;                  // 0..1
  const int lo4 = l & 15, hi2 = l >> 4;

  __shared__ _Float16 Kst[2][64][256];    // 64KB, src-swizzled
  __shared__ _Float16 Vst[2][256][64];    // 64KB, src-swizzled
  __shared__ _Float16 P[64 * 64];         // 8KB, XOR-swizzled rows
  __shared__ float pmax[2][64];

  const _Float16* qpk = (const _Float16*)dout + (size_t)(bb * 32 + qt) * 65536;
  const char*     kb  = (const char*)(kfp + (size_t)bb * SEQ * 512);
  const char*     vtb = (const char*)(vtp + (size_t)bb * (512 * 2048));

  const _Float16* qhi = qpk + (size_t)(qw * 16 + lo4) * 512;
  const _Float16* qlo = qhi + 32768;

  const int cnt = cntg[bb];
  const int nkt = (cnt + 63) >> 6;

#define STAGE_K(KT, H, B) do {                                                \
    const char* kg_ = kb + (size_t)(KT) * 64 * 1024;                          \
    char* lb_ = (char*)&Kst[(B)][0][0];                                       \
    _Pragma("unroll")                                                         \
    for (int i_ = 0; i_ < 4; i_++) {                                          \
      int D_ = i_ * 8192 + tid * 16;                                          \
      int row_ = D_ >> 9, cb_ = D_ & 511;                                     \
      GLDS16(kg_ + (size_t)row_ * 1024 + (H) * 512 +                          \
                 (cb_ ^ ((row_ & 7) << 4)),                                   \
             lb_ + D_);                                                       \
    } } while (0)

#define STAGE_V(KT, H, B) do {                                                \
    const char* vg_ = vtb + (size_t)(KT) * 128;                               \
    char* lb_ = (char*)&Vst[(B)][0][0];                                       \
    _Pragma("unroll")                                                         \
    for (int i_ = 0; i_ < 4; i_++) {                                          \
      int D_ = i_ * 8192 + tid * 16;                                          \
      int row_ = D_ >> 7, cb_ = D_ & 127;                                     \
      GLDS16(vg_ + (size_t)((H) * 256 + row_) * 4096 +                        \
                 (cb_ ^ ((row_ & 7) << 4)),                                   \
             lb_ + D_);                                                       \
    } } while (0)

#define QK_HALF(H, B) do {                                                    \
    const char* kl_ = (const char*)&Kst[(B)][0][0];                           \
    const int r0_ = kw * 32 + lo4, r1_ = r0_ + 16;                            \
    const int sw_ = (lo4 & 7) << 4;                                           \
    _Pragma("unroll")                                                         \
    for (int s_ = 0; s_ < 8; s_++) {                                          \
      const int dby_ = (s_ * 32 + hi2 * 8) * 2;                               \
      f16x8 k0 = *(const f16x8*)(kl_ + r0_ * 512 + (dby_ ^ sw_));             \
      f16x8 k1 = *(const f16x8*)(kl_ + r1_ * 512 + (dby_ ^ sw_));             \
      Sh[0] = MFMA16(fq[(H) * 8 + s_], k0, Sh[0]);                            \
      Sh[1] = MFMA16(fq[(H) * 8 + s_], k1, Sh[1]);                            \
      Sl[0] = MFMA16(fql[(H) * 8 + s_], k0, Sl[0]);                           \
      Sl[1] = MFMA16(fql[(H) * 8 + s_], k1, Sl[1]);                           \
    } } while (0)

#define PV_HALF(H, B) do {                                                    \
    const char* vl_ = (const char*)&Vst[(B)][0][0];                           \
    _Pragma("unroll")                                                         \
    for (int j_ = 0; j_ < 8; j_++) {                                          \
      const int dl_ = j_ * 32 + kw * 16 + lo4;                                \
      const int vs_ = (dl_ & 7) << 4;                                         \
      f16x8 v0 = *(const f16x8*)(vl_ + dl_ * 128 + ((hi2 * 16) ^ vs_));       \
      f16x8 v1 = *(const f16x8*)(vl_ + dl_ * 128 + ((64 + hi2 * 16) ^ vs_));  \
      o[(H) * 8 + j_] = MFMA16(pa[0], v0, o[(H) * 8 + j_]);                   \
      o[(H) * 8 + j_] = MFMA16(pa[1], v1, o[(H) * 8 + j_]);                   \
    } } while (0)

  // ---- prologue: Q hi+lo -> regs, stage kt0.h0, full drain ----
  f16x8 fq[16], fql[16];
  #pragma unroll
  for (int st = 0; st < 16; st++) {
    fq[st]  = *(const f16x8*)(qhi + st * 32 + hi2 * 8);
    fql[st] = *(const f16x8*)(qlo + st * 32 + hi2 * 8);
  }
  STAGE_K(0, 0, 0);
  __syncthreads();

  f32x4 o[16];
  #pragma unroll
  for (int f = 0; f < 16; f++)
    #pragma unroll
    for (int i = 0; i < 4; i++) o[f][i] = 0.f;
  f32x4 o_ones;
  #pragma unroll
  for (int i = 0; i < 4; i++) o_ones[i] = 0.f;

  f16x8 ones8;
  #pragma unroll
  for (int j = 0; j < 8; j++) ones8[j] = (_Float16)1.0f;

  float m_run[4], m_runP = -3.0e38f;
  #pragma unroll
  for (int i = 0; i < 4; i++) m_run[i] = -3.0e38f;

  const int ki0 = kw * 32 + lo4;
  const int ki1 = ki0 + 16;

  #pragma unroll 1
  for (int kt = 0; kt < nkt; kt++) {
    const int key0 = kt * 64;

    // ---- P1: issue K.h1 + V.h0; publish Ks[0] (prev E drained); QK h0 ----
    STAGE_K(kt, 1, 1);                    // A
    STAGE_V(kt, 0, 0);                    // C
    VM_BAR(8);                            // drains E(prev) -> Ks[0] ready

    f32x4 Sh[2], Sl[2];
    #pragma unroll
    for (int f = 0; f < 2; f++)
      #pragma unroll
      for (int i = 0; i < 4; i++) { Sh[f][i] = 0.f; Sl[f][i] = 0.f; }
    QK_HALF(0, 0);

    // ---- P2: publish Ks[1]; QK h1; issue V.h1 + K'.h0; local softmax ----
    VM_BAR(4);                            // drains A -> Ks[1] ready
    QK_HALF(1, 1);

    STAGE_V(kt, 1, 1);                    // D
    STAGE_K(kt + 1, 0, 0);                // E (last kt overruns: benign)

    f32x4 S[2];
    #pragma unroll
    for (int f = 0; f < 2; f++)
      #pragma unroll
      for (int i = 0; i < 4; i++) S[f][i] = Sh[f][i] + Sl[f][i];

    const bool t0 = (key0 + ki0 >= cnt);
    const bool t1 = (key0 + ki1 >= cnt);
    #pragma unroll
    for (int i = 0; i < 4; i++) {
      if (t0) S[0][i] = -1.0e9f;
      if (t1) S[1][i] = -1.0e9f;
      float mx = fmaxf(S[0][i], S[1][i]);
      #pragma unroll
      for (int off = 1; off < 16; off <<= 1)
        mx = fmaxf(mx, __shfl_xor(mx, off, 64));
      float p0 = __expf(S[0][i] - mx);
      float p1 = __expf(S[1][i] - mx);
      int row = qw*16 + hi2*4 + i;
      int swz = (row & 7) << 4;
      int b0  = (row*128 + (kw*32 + lo4)*2) ^ swz;
      int b1  = (row*128 + (kw*32 + 16 + lo4)*2) ^ swz;
      *(_Float16*)((char*)P + b0) = (_Float16)p0;
      *(_Float16*)((char*)P + b1) = (_Float16)p1;
      if (lo4 == 0) pmax[kw][row] = mx;
    }

    // ---- P3: publish Vst[0] + P + pmax ----
    VM_LGKM_BAR(8);                       // drains C -> Vst[0]; lgkm -> P/pmax

    // ---- P4: merge max; rescale only if any row max grew (oscale==1 else);
    //          scaled pa; sums via MFMA; PV ----
    float mn[4];
    bool grow = false;
    #pragma unroll
    for (int i = 0; i < 4; i++) {
      int row = qw*16 + hi2*4 + i;
      float m0 = pmax[0][row], m1 = pmax[1][row];
      mn[i] = fmaxf(m_run[i], fmaxf(m0, m1));
      grow = grow || (mn[i] > m_run[i]);
    }
    if (__any(grow)) {
      #pragma unroll
      for (int i = 0; i < 4; i++) {
        float osc = __expf(m_run[i] - mn[i]);
        m_run[i] = mn[i];
        #pragma unroll
        for (int f = 0; f < 16; f++) o[f][i] *= osc;
        o_ones[i] *= osc;
      }
    }

    f16x8 pa[2];
    {
      const int prow = qw*16 + lo4;
      float m0p = pmax[0][prow], m1p = pmax[1][prow];
      float mnp = fmaxf(m_runP, fmaxf(m0p, m1p));
      m_runP = mnp;
      _Float16 c0 = (_Float16)__expf(m0p - mnp);
      _Float16 c1 = (_Float16)__expf(m1p - mnp);
      const int psw = (prow & 7) << 4;
      pa[0] = *(const f16x8*)((const char*)P + prow*128 + ((hi2*16) ^ psw));
      pa[1] = *(const f16x8*)((const char*)P + prow*128 + ((64 + hi2*16) ^ psw));
      pa[0] = pa[0] * c0;
      pa[1] = pa[1] * c1;
    }

    // row-sums: o_ones += P @ 1
    o_ones = MFMA16(pa[0], ones8, o_ones);
    o_ones = MFMA16(pa[1], ones8, o_ones);

    PV_HALF(0, 0);
    VM_BAR(4);                            // drains D -> Vst[1] ready (E stays)
    PV_HALF(1, 1);
  }
#undef STAGE_K
#undef STAGE_V
#undef QK_HALF
#undef PV_HALF

  asm volatile("s_waitcnt vmcnt(0)" ::: "memory");

  // ---- epilogue: normalize by o_ones and store ----
  #pragma unroll
  for (int i = 0; i < 4; i++) {
    float inv = 1.0f / o_ones[i];
    int rowg = bb * SEQ + q0 + qw*16 + hi2*4 + i;
    #pragma unroll
    for (int h = 0; h < 2; h++)
      #pragma unroll
      for (int j = 0; j < 8; j++) {
        int d = h*256 + j*32 + kw*16 + lo4;
        dout[(size_t)rowg * 512 + d] = o[h*8 + j][i] * inv;
      }
  }
}

extern "C" void kernel_launch(void* const* d_in, const int* in_sizes, int n_in,
                              void* d_out, int out_size, void* d_ws, size_t ws_size,
                              hipStream_t stream)
{
  const float* x    = (const float*)d_in[0];
  const float* Wq   = (const float*)d_in[1];
  const float* Wk   = (const float*)d_in[2];
  const float* Wv   = (const float*)d_in[3];
  const int*   mask = (const int*)d_in[4];

  _Float16* wsh = (_Float16*)d_ws;
  _Float16* KF = wsh;                  //  8,388,608 halfs (K fp16 compacted)
  _Float16* VT = wsh +  8388608;       //  8,388,608 halfs (V^T fp16 compacted)
  _Float16* WT = wsh + 16777216;       //  1,572,864 halfs (W^T fp16)
  _Float16* XH = wsh + 18350080;       // 16,777,216 halfs (X fp16)
  int* PIDX    = (int*)(wsh + 35127296);   // 16,384 ints
  int* CNT     = PIDX + 16384;             // 8 ints -> ~70.4 MB total

  prep_all<<<9736, 256, 0, stream>>>(x, XH, Wq, Wk, Wv, WT, mask, PIDX, CNT);

  dim3 pgrid(2, 128);
  proj3<<<pgrid, 512, 0, stream>>>(XH, WT, PIDX, KF, VT, (_Float16*)d_out);

  flash_v10<<<256, 512, 0, stream>>>(KF, VT, CNT, (float*)d_out);
}

// Round 18
// 238.682 us; speedup vs baseline: 1.2738x; 1.2738x over previous
//
#include <hip/hip_runtime.h>
#include <hip/hip_bf16.h>
#include <cstddef>
#include <cstdint>

#define BATCH 8
#define SEQ   2048
#define DEMB  1024
#define DQ    512

typedef __attribute__((ext_vector_type(8))) _Float16 f16x8;
typedef __attribute__((ext_vector_type(4))) float f32x4;

#define MFMA16(a, b, c) __builtin_amdgcn_mfma_f32_16x16x32_f16((a), (b), (c), 0, 0, 0)

#define GLDS16(gp, lp) __builtin_amdgcn_global_load_lds(                      \
    (const __attribute__((address_space(1))) void*)(gp),                      \
    (__attribute__((address_space(3))) void*)(lp), 16, 0, 0)

#define VM_BAR(N)                                                             \
  asm volatile("s_waitcnt vmcnt(" #N ")\n\ts_barrier" ::: "memory")
#define VM_LGKM_BAR(N)                                                        \
  asm volatile("s_waitcnt vmcnt(" #N ") lgkmcnt(0)\n\ts_barrier" ::: "memory")

// ---------------------------------------------------------------------------
// Merged prep: blocks [0,8192) xprep; [8192,9728) wprep; [9728,9736) mprep.
// ---------------------------------------------------------------------------
__global__ __launch_bounds__(256) void prep_all(
    const float* __restrict__ x, _Float16* __restrict__ xh,
    const float* __restrict__ Wq, const float* __restrict__ Wk,
    const float* __restrict__ Wv, _Float16* __restrict__ wt,
    const int* __restrict__ maskg, int* __restrict__ pidx,
    int* __restrict__ cnt)
{
  const int bid = blockIdx.x;
  const int tid = threadIdx.x;

  if (bid < 8192) {
    size_t i = ((size_t)bid * 256 + tid) * 8;
    float4 a = *(const float4*)&x[i];
    float4 b = *(const float4*)&x[i + 4];
    f16x8 h;
    h[0] = (_Float16)a.x; h[1] = (_Float16)a.y;
    h[2] = (_Float16)a.z; h[3] = (_Float16)a.w;
    h[4] = (_Float16)b.x; h[5] = (_Float16)b.y;
    h[6] = (_Float16)b.z; h[7] = (_Float16)b.w;
    *(f16x8*)&xh[i] = h;
  } else if (bid < 9728) {
    int qidx = (bid - 8192) * 256 + tid;
    int w   = qidx >> 17;
    int rem = qidx & 131071;
    int k   = rem >> 7;
    int n   = (rem & 127) * 4;
    const float* W = (w == 0) ? Wq : (w == 1) ? Wk : Wv;
    float4 v = *(const float4*)&W[(size_t)k * DQ + n];
    _Float16* dst = wt + (size_t)w * (DQ * DEMB);
    dst[(size_t)(n + 0) * DEMB + k] = (_Float16)v.x;
    dst[(size_t)(n + 1) * DEMB + k] = (_Float16)v.y;
    dst[(size_t)(n + 2) * DEMB + k] = (_Float16)v.z;
    dst[(size_t)(n + 3) * DEMB + k] = (_Float16)v.w;
  } else {
    const int b = bid - 9728;
    __shared__ int tsum[256];
    int mv[8], s = 0;
    #pragma unroll
    for (int j = 0; j < 8; j++) {
      mv[j] = maskg[b * SEQ + tid * 8 + j];
      s += mv[j];
    }
    tsum[tid] = s;
    __syncthreads();
    for (int d = 1; d < 256; d <<= 1) {
      int v = (tid >= d) ? tsum[tid - d] : 0;
      __syncthreads();
      tsum[tid] += v;
      __syncthreads();
    }
    if (tid == 255) cnt[b] = tsum[255];
    int run = tsum[tid] - s;
    #pragma unroll
    for (int j = 0; j < 8; j++) {
      pidx[b * SEQ + tid * 8 + j] = mv[j] ? run : -1;
      run += mv[j];
    }
  }
}

// ---------------------------------------------------------------------------
// Projection GEMM 3-in-1 (r16 verbatim, no setprio).
// ---------------------------------------------------------------------------
__global__ __launch_bounds__(512, 2) void proj3(
    const _Float16* __restrict__ xh, const _Float16* __restrict__ wt,
    const int* __restrict__ pidx,
    _Float16* __restrict__ kf, _Float16* __restrict__ vt,
    _Float16* __restrict__ qpack)
{
  const int mt = blockIdx.y, nt = blockIdx.x;

  __shared__ _Float16 Xs[128][40];       // 10KB
  __shared__ _Float16 Ws[3][256][40];    // 60KB

  const int tid  = threadIdx.x;
  const int wave = tid >> 6, l = tid & 63;
  const int wm = wave >> 2;              // 0..1  (64-row group)
  const int wn = wave & 3;               // 0..3  (64-col group)
  const int lo4 = l & 15, hi2 = l >> 4;

  f32x4 acc[3][4][4];
  #pragma unroll
  for (int w = 0; w < 3; w++)
    #pragma unroll
    for (int mf = 0; mf < 4; mf++)
      #pragma unroll
      for (int nf = 0; nf < 4; nf++)
        #pragma unroll
        for (int i = 0; i < 4; i++) acc[w][mf][nf][i] = 0.f;

  const int    xsrow = tid >> 2;
  const int    xskh  = (tid & 3) * 8;
  const size_t xbase = (size_t)(mt * 128 + xsrow) * DEMB + xskh;
  const int    wsrow = tid >> 1;
  const int    wskh  = (tid & 1) * 16;
  const size_t wbase = (size_t)(nt * 256 + wsrow) * DEMB + wskh;

  #pragma unroll 1
  for (int k0 = 0; k0 < DEMB; k0 += 32) {
    *(f16x8*)&Xs[xsrow][xskh] = *(const f16x8*)&xh[xbase + k0];
    #pragma unroll
    for (int w = 0; w < 3; w++) {
      const size_t wb = (size_t)w * (DQ * DEMB) + wbase + k0;
      *(f16x8*)&Ws[w][wsrow][wskh]     = *(const f16x8*)&wt[wb];
      *(f16x8*)&Ws[w][wsrow][wskh + 8] = *(const f16x8*)&wt[wb + 8];
    }
    __syncthreads();

    f16x8 a[4];
    #pragma unroll
    for (int mf = 0; mf < 4; mf++)
      a[mf] = *(const f16x8*)&Xs[wm*64 + mf*16 + lo4][hi2*8];
    #pragma unroll
    for (int w = 0; w < 3; w++) {
      f16x8 bfr[4];
      #pragma unroll
      for (int nf = 0; nf < 4; nf++)
        bfr[nf] = *(const f16x8*)&Ws[w][wn*64 + nf*16 + lo4][hi2*8];
      #pragma unroll
      for (int mf = 0; mf < 4; mf++)
        #pragma unroll
        for (int nf = 0; nf < 4; nf++)
          acc[w][mf][nf] = MFMA16(a[mf], bfr[nf], acc[w][mf][nf]);
    }
    __syncthreads();
  }

  const int mb = mt * 128 + wm * 64;
  const int nb = nt * 256 + wn * 64;
  #pragma unroll
  for (int mf = 0; mf < 4; mf++)
    #pragma unroll
    for (int nf = 0; nf < 4; nf++)
      #pragma unroll
      for (int i = 0; i < 4; i++) {
        int m = mb + mf*16 + hi2*4 + i;
        int n = nb + nf*16 + lo4;
        {
          float val = acc[0][mf][nf][i];
          _Float16 h  = (_Float16)val;
          _Float16 lo = (_Float16)(val - (float)h);
          size_t base = (size_t)(m >> 6) * 65536 + (size_t)(m & 63) * 512 + n;
          qpack[base]         = h;
          qpack[base + 32768] = lo;
        }
        int d_ = pidx[m];
        if (d_ >= 0) {
          kf[((size_t)((m >> 11) << 11) + d_) * 512 + n]
              = (_Float16)acc[1][mf][nf][i];
          vt[(size_t)(m >> 11) * (512 * 2048) + (size_t)n * 2048 + d_]
              = (_Float16)acc[2][mf][nf][i];
        }
      }
}

// ---------------------------------------------------------------------------
// Flash attention v9b = r15's validated 150µs flash_v9 with EXACTLY one
// change: s_setprio pairs removed (m190: setprio is mildly negative on
// lockstep barrier-synced structures). Timing-uniform -> lockstep L2 reuse
// (FETCH ~36MB) must be preserved; that counter is the discriminator.
// ---------------------------------------------------------------------------
__global__ __launch_bounds__(512, 2) void flash_v9b(
    const _Float16* __restrict__ kfp, const _Float16* __restrict__ vtp,
    const int* __restrict__ cntg,
    float* dout)                          // aliases Q storage - no restrict
{
  const int bb = blockIdx.x & 7;          // batch -> XCD pin
  const int qt = blockIdx.x >> 3;         // 0..31
  const int q0 = qt * 64;

  const int tid = threadIdx.x;
  const int w = tid >> 6, l = tid & 63;
  const int qw = w & 3;                   // 16-row group
  const int kw = w >> 2;                  // 0..1
  const int lo4 = l & 15, hi2 = l >> 4;

  __shared__ _Float16 Kst[2][64][256];    // 64KB, src-swizzled
  __shared__ _Float16 Vst[2][256][64];    // 64KB, src-swizzled
  __shared__ _Float16 P[64 * 64];         // 8KB, XOR-swizzled rows
  __shared__ float pmax[2][64];

  const _Float16* qpk = (const _Float16*)dout + (size_t)(bb * 32 + qt) * 65536;
  const char*     kb  = (const char*)(kfp + (size_t)bb * SEQ * 512);
  const char*     vtb = (const char*)(vtp + (size_t)bb * (512 * 2048));

  const _Float16* qhi = qpk + (size_t)(qw * 16 + lo4) * 512;
  const _Float16* qlo = qhi + 32768;

  const int cnt = cntg[bb];
  const int nkt = (cnt + 63) >> 6;

#define STAGE_K(KT, H, B) do {                                                \
    const char* kg_ = kb + (size_t)(KT) * 64 * 1024;                          \
    char* lb_ = (char*)&Kst[(B)][0][0];                                       \
    _Pragma("unroll")                                                         \
    for (int i_ = 0; i_ < 4; i_++) {                                          \
      int D_ = i_ * 8192 + tid * 16;                                          \
      int row_ = D_ >> 9, cb_ = D_ & 511;                                     \
      GLDS16(kg_ + (size_t)row_ * 1024 + (H) * 512 +                          \
                 (cb_ ^ ((row_ & 7) << 4)),                                   \
             lb_ + D_);                                                       \
    } } while (0)

#define STAGE_V(KT, H, B) do {                                                \
    const char* vg_ = vtb + (size_t)(KT) * 128;                               \
    char* lb_ = (char*)&Vst[(B)][0][0];                                       \
    _Pragma("unroll")                                                         \
    for (int i_ = 0; i_ < 4; i_++) {                                          \
      int D_ = i_ * 8192 + tid * 16;                                          \
      int row_ = D_ >> 7, cb_ = D_ & 127;                                     \
      GLDS16(vg_ + (size_t)((H) * 256 + row_) * 4096 +                        \
                 (cb_ ^ ((row_ & 7) << 4)),                                   \
             lb_ + D_);                                                       \
    } } while (0)

#define QK_HALF(H, B) do {                                                    \
    const char* kl_ = (const char*)&Kst[(B)][0][0];                           \
    const int r0_ = kw * 32 + lo4, r1_ = r0_ + 16;                            \
    const int sw_ = (lo4 & 7) << 4;                                           \
    _Pragma("unroll")                                                         \
    for (int s_ = 0; s_ < 8; s_++) {                                          \
      const int dby_ = (s_ * 32 + hi2 * 8) * 2;                               \
      f16x8 k0 = *(const f16x8*)(kl_ + r0_ * 512 + (dby_ ^ sw_));             \
      f16x8 k1 = *(const f16x8*)(kl_ + r1_ * 512 + (dby_ ^ sw_));             \
      S[0] = MFMA16(fq[(H) * 8 + s_], k0, S[0]);                              \
      S[1] = MFMA16(fq[(H) * 8 + s_], k1, S[1]);                              \
      S[0] = MFMA16(fql[(H) * 8 + s_], k0, S[0]);                             \
      S[1] = MFMA16(fql[(H) * 8 + s_], k1, S[1]);                             \
    } } while (0)

#define PV_HALF(H, B) do {                                                    \
    const char* vl_ = (const char*)&Vst[(B)][0][0];                           \
    _Pragma("unroll")                                                         \
    for (int j_ = 0; j_ < 8; j_++) {                                          \
      const int dl_ = j_ * 32 + kw * 16 + lo4;                                \
      const int vs_ = (dl_ & 7) << 4;                                         \
      f16x8 v0 = *(const f16x8*)(vl_ + dl_ * 128 + ((hi2 * 16) ^ vs_));       \
      f16x8 v1 = *(const f16x8*)(vl_ + dl_ * 128 + ((64 + hi2 * 16) ^ vs_));  \
      o[(H) * 8 + j_] = MFMA16(pa[0], v0, o[(H) * 8 + j_]);                   \
      o[(H) * 8 + j_] = MFMA16(pa[1], v1, o[(H) * 8 + j_]);                   \
    } } while (0)

  // ---- prologue: Q hi+lo -> regs, stage kt0.h0, full drain ----
  f16x8 fq[16], fql[16];
  #pragma unroll
  for (int st = 0; st < 16; st++) {
    fq[st]  = *(const f16x8*)(qhi + st * 32 + hi2 * 8);
    fql[st] = *(const f16x8*)(qlo + st * 32 + hi2 * 8);
  }
  STAGE_K(0, 0, 0);
  __syncthreads();

  f32x4 o[16];
  #pragma unroll
  for (int f = 0; f < 16; f++)
    #pragma unroll
    for (int i = 0; i < 4; i++) o[f][i] = 0.f;
  f32x4 o_ones;
  #pragma unroll
  for (int i = 0; i < 4; i++) o_ones[i] = 0.f;

  f16x8 ones8;
  #pragma unroll
  for (int j = 0; j < 8; j++) ones8[j] = (_Float16)1.0f;

  float m_run[4], m_runP = -3.0e38f;
  #pragma unroll
  for (int i = 0; i < 4; i++) m_run[i] = -3.0e38f;

  const int ki0 = kw * 32 + lo4;
  const int ki1 = ki0 + 16;

  #pragma unroll 1
  for (int kt = 0; kt < nkt; kt++) {
    const int key0 = kt * 64;

    // ---- P1: issue K.h1 + V.h0; publish Ks[0] (prev E drained); QK h0 ----
    STAGE_K(kt, 1, 1);                    // A
    STAGE_V(kt, 0, 0);                    // C
    VM_BAR(8);                            // drains E(prev) -> Ks[0] ready

    f32x4 S[2];
    #pragma unroll
    for (int f = 0; f < 2; f++)
      #pragma unroll
      for (int i = 0; i < 4; i++) S[f][i] = 0.f;
    QK_HALF(0, 0);

    // ---- P2: publish Ks[1]; QK h1; issue V.h1 + K'.h0; local softmax ----
    VM_BAR(4);                            // drains A -> Ks[1] ready
    QK_HALF(1, 1);

    STAGE_V(kt, 1, 1);                    // D
    STAGE_K(kt + 1, 0, 0);                // E (last kt overruns: benign)

    const bool t0 = (key0 + ki0 >= cnt);
    const bool t1 = (key0 + ki1 >= cnt);
    #pragma unroll
    for (int i = 0; i < 4; i++) {
      if (t0) S[0][i] = -1.0e9f;
      if (t1) S[1][i] = -1.0e9f;
      float mx = fmaxf(S[0][i], S[1][i]);
      #pragma unroll
      for (int off = 1; off < 16; off <<= 1)
        mx = fmaxf(mx, __shfl_xor(mx, off, 64));
      float p0 = __expf(S[0][i] - mx);
      float p1 = __expf(S[1][i] - mx);
      int row = qw*16 + hi2*4 + i;
      int swz = (row & 7) << 4;
      int b0  = (row*128 + (kw*32 + lo4)*2) ^ swz;
      int b1  = (row*128 + (kw*32 + 16 + lo4)*2) ^ swz;
      *(_Float16*)((char*)P + b0) = (_Float16)p0;
      *(_Float16*)((char*)P + b1) = (_Float16)p1;
      if (lo4 == 0) pmax[kw][row] = mx;
    }

    // ---- P3: publish Vst[0] + P + pmax ----
    VM_LGKM_BAR(8);                       // drains C -> Vst[0]; lgkm -> P/pmax

    // ---- P4: merge max, rescale o+o_ones, scaled pa; sums via MFMA; PV ----
    float oscale[4];
    #pragma unroll
    for (int i = 0; i < 4; i++) {
      int row = qw*16 + hi2*4 + i;
      float m0 = pmax[0][row], m1 = pmax[1][row];
      float mn = fmaxf(m_run[i], fmaxf(m0, m1));
      oscale[i] = __expf(m_run[i] - mn);
      m_run[i] = mn;
    }
    #pragma unroll
    for (int f = 0; f < 16; f++)
      #pragma unroll
      for (int i = 0; i < 4; i++) o[f][i] *= oscale[i];
    #pragma unroll
    for (int i = 0; i < 4; i++) o_ones[i] *= oscale[i];

    f16x8 pa[2];
    {
      const int prow = qw*16 + lo4;
      float m0p = pmax[0][prow], m1p = pmax[1][prow];
      float mnp = fmaxf(m_runP, fmaxf(m0p, m1p));
      m_runP = mnp;
      _Float16 c0 = (_Float16)__expf(m0p - mnp);
      _Float16 c1 = (_Float16)__expf(m1p - mnp);
      const int psw = (prow & 7) << 4;
      pa[0] = *(const f16x8*)((const char*)P + prow*128 + ((hi2*16) ^ psw));
      pa[1] = *(const f16x8*)((const char*)P + prow*128 + ((64 + hi2*16) ^ psw));
      pa[0] = pa[0] * c0;
      pa[1] = pa[1] * c1;
    }

    // row-sums: o_ones += P @ 1  (2 MFMAs replace the shuffle reduce)
    o_ones = MFMA16(pa[0], ones8, o_ones);
    o_ones = MFMA16(pa[1], ones8, o_ones);

    PV_HALF(0, 0);
    VM_BAR(4);                            // drains D -> Vst[1] ready (E stays)
    PV_HALF(1, 1);
  }
#undef STAGE_K
#undef STAGE_V
#undef QK_HALF
#undef PV_HALF

  asm volatile("s_waitcnt vmcnt(0)" ::: "memory");

  // ---- epilogue: normalize by o_ones and store ----
  #pragma unroll
  for (int i = 0; i < 4; i++) {
    float inv = 1.0f / o_ones[i];
    int rowg = bb * SEQ + q0 + qw*16 + hi2*4 + i;
    #pragma unroll
    for (int h = 0; h < 2; h++)
      #pragma unroll
      for (int j = 0; j < 8; j++) {
        int d = h*256 + j*32 + kw*16 + lo4;
        dout[(size_t)rowg * 512 + d] = o[h*8 + j][i] * inv;
      }
  }
}

extern "C" void kernel_launch(void* const* d_in, const int* in_sizes, int n_in,
                              void* d_out, int out_size, void* d_ws, size_t ws_size,
                              hipStream_t stream)
{
  const float* x    = (const float*)d_in[0];
  const float* Wq   = (const float*)d_in[1];
  const float* Wk   = (const float*)d_in[2];
  const float* Wv   = (const float*)d_in[3];
  const int*   mask = (const int*)d_in[4];

  _Float16* wsh = (_Float16*)d_ws;
  _Float16* KF = wsh;                  //  8,388,608 halfs (K fp16 compacted)
  _Float16* VT = wsh +  8388608;       //  8,388,608 halfs (V^T fp16 compacted)
  _Float16* WT = wsh + 16777216;       //  1,572,864 halfs (W^T fp16)
  _Float16* XH = wsh + 18350080;       // 16,777,216 halfs (X fp16)
  int* PIDX    = (int*)(wsh + 35127296);   // 16,384 ints
  int* CNT     = PIDX + 16384;             // 8 ints -> ~70.4 MB total

  prep_all<<<9736, 256, 0, stream>>>(x, XH, Wq, Wk, Wv, WT, mask, PIDX, CNT);

  dim3 pgrid(2, 128);
  proj3<<<pgrid, 512, 0, stream>>>(XH, WT, PIDX, KF, VT, (_Float16*)d_out);

  flash_v9b<<<256, 512, 0, stream>>>(KF, VT, CNT, (float*)d_out);
}